// Round 4
// baseline (185.242 us; speedup 1.0000x reference)
//
#include <hip/hip_runtime.h>

#define IN_DIM   256
#define HID_DIM  512
#define OUT_DIM  256
#define N_CHILD  8
#define BATCH    1024

// agent_indices may be int32 or int64 (jax_enable_x64). Detect at runtime:
// view buffer as int32. First 1024 words are in-bounds for BOTH dtypes
// (int32: 1024 values; int64: 512 {lo,hi} pairs). If ANY odd word != 0 the
// data is int32 (odd slots are random agents 0..63); if all are 0 it's int64
// (odd slots are high words). P(false int64 | int32) = 64^-512 ~ 0.
extern "C" __global__ __launch_bounds__(1024)
void normalize_idx(const int* __restrict__ raw, int* __restrict__ norm)
{
    __shared__ int is32;
    const int t = threadIdx.x;
    if (t == 0) is32 = 0;
    __syncthreads();
    if (raw[2 * (t & 511) + 1] != 0) is32 = 1;   // benign shared race
    __syncthreads();
    norm[t] = (is32 ? raw[t] : raw[2 * t]) & 63; // &63: fault insurance
}

// One block per sample, 256 threads. fp32 inputs, fp32 accumulation; h kept in
// LDS (fp32) so phases 2/3 consume unrounded h. Outputs written as FP32
// (reference output dtype is float32 -> d_out is float*).
extern "C" __global__ __launch_bounds__(256)
void hierarchy_fused(const float* __restrict__ x,
                     const float* __restrict__ W1,
                     const float* __restrict__ b1,
                     const float* __restrict__ W2,
                     const float* __restrict__ b2,
                     const float* __restrict__ rw,
                     const int* __restrict__ agent_indices, // normalized int32
                     float* __restrict__ h_out,             // [B, HID]
                     float* __restrict__ o_out,             // [B, OUT]
                     float* __restrict__ r_out)             // [B, C]
{
    const int s = blockIdx.x;
    const int t = threadIdx.x;
    const int a = agent_indices[s];

    __shared__ float xs[IN_DIM];          // x[s] in fp32
    __shared__ float hs[HID_DIM];         // fp32 h
    __shared__ float sc[3 * OUT_DIM];     // 768 floats of reduction scratch

    xs[t] = x[(size_t)s * IN_DIM + t];
    __syncthreads();

    // ---- phase 1: h = relu(x @ W1[a] + b1[a])  (256 -> 512) ----
    {
        const float* w1 = W1 + (size_t)a * IN_DIM * HID_DIM;
        const int c  = 4 * (t & 127);
        const int kh = t >> 7;                     // 0 or 1
        const float* p = w1 + (size_t)(kh * 128) * HID_DIM + c;
        float4 acc = make_float4(0.f, 0.f, 0.f, 0.f);
        #pragma unroll 4
        for (int k = 0; k < 128; ++k) {
            const float4 w = *(const float4*)p;
            const float xv = xs[kh * 128 + k];     // LDS broadcast
            acc.x = fmaf(xv, w.x, acc.x);
            acc.y = fmaf(xv, w.y, acc.y);
            acc.z = fmaf(xv, w.z, acc.z);
            acc.w = fmaf(xv, w.w, acc.w);
            p += HID_DIM;
        }
        if (kh) *(float4*)(sc + c) = acc;
        __syncthreads();
        if (!kh) {
            const float4 o = *(const float4*)(sc + c);
            float r0 = fmaxf(acc.x + o.x + b1[a * HID_DIM + c],     0.f);
            float r1 = fmaxf(acc.y + o.y + b1[a * HID_DIM + c + 1], 0.f);
            float r2 = fmaxf(acc.z + o.z + b1[a * HID_DIM + c + 2], 0.f);
            float r3 = fmaxf(acc.w + o.w + b1[a * HID_DIM + c + 3], 0.f);
            hs[c]     = r0;  hs[c + 1] = r1;
            hs[c + 2] = r2;  hs[c + 3] = r3;
            *(float4*)(h_out + (size_t)s * HID_DIM + c) = make_float4(r0, r1, r2, r3);
        }
    }
    __syncthreads();   // hs ready for all; sc free for reuse

    // ---- phase 2: out = h @ W2[a] + b2[a]  (512 -> 256) ----
    {
        const float* w2 = W2 + (size_t)a * HID_DIM * OUT_DIM;
        const int c  = 4 * (t & 63);
        const int kq = t >> 6;                     // 0..3
        const float* p = w2 + (size_t)(kq * 128) * OUT_DIM + c;
        float4 acc = make_float4(0.f, 0.f, 0.f, 0.f);
        #pragma unroll 4
        for (int k = 0; k < 128; ++k) {
            const float4 w = *(const float4*)p;
            const float hv = hs[kq * 128 + k];     // LDS broadcast
            acc.x = fmaf(hv, w.x, acc.x);
            acc.y = fmaf(hv, w.y, acc.y);
            acc.z = fmaf(hv, w.z, acc.z);
            acc.w = fmaf(hv, w.w, acc.w);
            p += OUT_DIM;
        }
        if (kq) *(float4*)(sc + (size_t)(kq - 1) * OUT_DIM + c) = acc;
        __syncthreads();
        if (!kq) {
            #pragma unroll
            for (int q = 0; q < 3; ++q) {
                const float4 o = *(const float4*)(sc + (size_t)q * OUT_DIM + c);
                acc.x += o.x; acc.y += o.y; acc.z += o.z; acc.w += o.w;
            }
            acc.x += b2[a * OUT_DIM + c];
            acc.y += b2[a * OUT_DIM + c + 1];
            acc.z += b2[a * OUT_DIM + c + 2];
            acc.w += b2[a * OUT_DIM + c + 3];
            *(float4*)(o_out + (size_t)s * OUT_DIM + c) = acc;
        }
    }
    __syncthreads();   // sc free for reuse

    // ---- phase 3: r_logits = h @ rw[a]  (512 -> 8) ----
    {
        const float* rwa = rw + (size_t)a * HID_DIM * N_CHILD;
        const int rc = t & 7;
        const int ks = t >> 3;                     // 0..31
        float rp = 0.f;
        #pragma unroll
        for (int i = 0; i < HID_DIM / 32; ++i) {   // 16 iters
            const int k = ks * 16 + i;
            rp = fmaf(hs[k], rwa[(size_t)k * N_CHILD + rc], rp);
        }
        sc[t] = rp;
        __syncthreads();
        if (t < N_CHILD) {
            float r = 0.f;
            #pragma unroll
            for (int i = 0; i < 32; ++i) r += sc[t + N_CHILD * i];
            r_out[(size_t)s * N_CHILD + t] = r;
        }
    }
}

extern "C" void kernel_launch(void* const* d_in, const int* in_sizes, int n_in,
                              void* d_out, int out_size, void* d_ws, size_t ws_size,
                              hipStream_t stream) {
    const float* x  = (const float*)d_in[0];
    const float* W1 = (const float*)d_in[1];
    const float* b1 = (const float*)d_in[2];
    const float* W2 = (const float*)d_in[3];
    const float* b2 = (const float*)d_in[4];
    const float* rw = (const float*)d_in[5];
    const int* raw  = (const int*)d_in[6];

    int* idx_norm = (int*)d_ws;   // BATCH int32

    float* out   = (float*)d_out;
    float* h_out = out;                                   // [B, HID]
    float* o_out = h_out + (size_t)BATCH * HID_DIM;       // [B, OUT]
    float* r_out = o_out + (size_t)BATCH * OUT_DIM;       // [B, C]

    hipLaunchKernelGGL(normalize_idx, dim3(1), dim3(BATCH), 0, stream,
                       raw, idx_norm);
    hipLaunchKernelGGL(hierarchy_fused, dim3(BATCH), dim3(256), 0, stream,
                       x, W1, b1, W2, b2, rw, idx_norm, h_out, o_out, r_out);
}